// Round 1
// baseline (438.787 us; speedup 1.0000x reference)
//
#include <hip/hip_runtime.h>

// NLinear: out[b,n,o] = sum_i x[b,n,i] * w[n,i,o] + bias[n,o]
// B=4096, N=200, D_IN=D_OUT=64.  Pure fp32 vector kernel.
// Roofline: ~440 MB HBM traffic -> ~68 us floor; VALU fp32 floor ~43 us.

#define B_DIM 4096
#define N_DIM 200
#define D 64                    // D_IN == D_OUT
#define ROWS_PER_BLOCK 128      // b-rows per block
#define CHUNK 32                // rows staged into LDS per iteration
#define NWAVES 4                // 256 threads
#define ROWS_PER_WAVE (CHUNK / NWAVES)  // 8

__global__ __launch_bounds__(256, 4)
void nlinear_kernel(const float* __restrict__ x,
                    const float* __restrict__ w,
                    const float* __restrict__ bias,
                    float* __restrict__ out) {
    const int n    = blockIdx.y;
    const int b0   = blockIdx.x * ROWS_PER_BLOCK;
    const int tid  = threadIdx.x;
    const int lane = tid & 63;
    const int wave = tid >> 6;

    __shared__ float x_lds[CHUNK][D];   // 8 KB

    // Lane `lane` (same in every wave) holds weight column w[n][:, lane] in
    // registers.  Per-instr access is 64 lanes * 4B contiguous = coalesced;
    // all blocks with the same n read the same 16 KB -> L1/L2 hot.
    const float* wn = w + (size_t)n * (D * D);
    float wreg[D];
#pragma unroll
    for (int i = 0; i < D; ++i) wreg[i] = wn[i * D + lane];

    const float bv = bias[n * D + lane];

    const size_t row_stride = (size_t)N_DIM * D;          // 12800 floats
    const float* xb = x   + (size_t)b0 * row_stride + (size_t)n * D;
    float*       ob = out + (size_t)b0 * row_stride + (size_t)n * D;

    for (int c0 = 0; c0 < ROWS_PER_BLOCK; c0 += CHUNK) {
        // Stage CHUNK rows (32 x 64 floats = 512 float4) with 256 threads,
        // 2 float4 each.  16 float4 per row -> coalesced 256B segments.
#pragma unroll
        for (int k = 0; k < 2; ++k) {
            const int idx = tid + k * 256;      // float4 index 0..511
            const int r   = idx >> 4;           // row within chunk
            const int f   = (idx & 15) << 2;    // float offset within row
            const float4 v = *(const float4*)(xb + (size_t)(c0 + r) * row_stride + f);
            *(float4*)(&x_lds[r][f]) = v;
        }
        __syncthreads();

        // Each wave computes ROWS_PER_WAVE rows; lane o computes out[., n, o].
#pragma unroll
        for (int rr = 0; rr < ROWS_PER_WAVE; ++rr) {
            const int r = wave * ROWS_PER_WAVE + rr;
            const float* xr = &x_lds[r][0];
            float a0 = 0.f, a1 = 0.f, a2 = 0.f, a3 = 0.f;
#pragma unroll
            for (int i = 0; i < D; i += 16) {
                // Same-address (wave-uniform) b128 reads -> LDS broadcast,
                // conflict-free.
                const float4 v0 = *(const float4*)(xr + i);
                const float4 v1 = *(const float4*)(xr + i + 4);
                const float4 v2 = *(const float4*)(xr + i + 8);
                const float4 v3 = *(const float4*)(xr + i + 12);
                a0 = fmaf(v0.x, wreg[i + 0], a0);
                a0 = fmaf(v0.y, wreg[i + 1], a0);
                a0 = fmaf(v0.z, wreg[i + 2], a0);
                a0 = fmaf(v0.w, wreg[i + 3], a0);
                a1 = fmaf(v1.x, wreg[i + 4], a1);
                a1 = fmaf(v1.y, wreg[i + 5], a1);
                a1 = fmaf(v1.z, wreg[i + 6], a1);
                a1 = fmaf(v1.w, wreg[i + 7], a1);
                a2 = fmaf(v2.x, wreg[i + 8], a2);
                a2 = fmaf(v2.y, wreg[i + 9], a2);
                a2 = fmaf(v2.z, wreg[i + 10], a2);
                a2 = fmaf(v2.w, wreg[i + 11], a2);
                a3 = fmaf(v3.x, wreg[i + 12], a3);
                a3 = fmaf(v3.y, wreg[i + 13], a3);
                a3 = fmaf(v3.z, wreg[i + 14], a3);
                a3 = fmaf(v3.w, wreg[i + 15], a3);
            }
            // Coalesced 256B store per instr.
            ob[(size_t)(c0 + r) * row_stride + lane] = ((a0 + a1) + (a2 + a3)) + bv;
        }
        __syncthreads();
    }
}

extern "C" void kernel_launch(void* const* d_in, const int* in_sizes, int n_in,
                              void* d_out, int out_size, void* d_ws, size_t ws_size,
                              hipStream_t stream) {
    const float* x    = (const float*)d_in[0];   // (4096, 200, 64)
    const float* w    = (const float*)d_in[1];   // (1, 200, 64, 64)
    const float* bias = (const float*)d_in[2];   // (1, 200, 64)
    float*       out  = (float*)d_out;           // (4096, 200, 64)

    dim3 grid(B_DIM / ROWS_PER_BLOCK, N_DIM);    // 32 x 200 = 6400 blocks
    nlinear_kernel<<<grid, dim3(256), 0, stream>>>(x, w, bias, out);
}